// Round 2
// baseline (132.760 us; speedup 1.0000x reference)
//
#include <hip/hip_runtime.h>

// Problem constants (B,C,H,W)=(2,256,56,56), Cr=64, K=7, G=16, stride=1
#define HW     3136          // 56*56
#define C_IN   256
#define CR     64
#define KKG    784           // 49*16
#define NB     2             // batch
#define NPIX   6272          // NB*HW
#define NT25   25            // p-tiles of 256 over NPIX
#define BN_EPS 1e-5f

// Device-global scratch (fully rewritten every call; no cross-call state)
__device__ float g_T[CR * NPIX];           // conv1 output (pre-BN) [o][p]
__device__ float g_bs[2 * CR * NT25];      // per-block partial sum/sumsq [2][o][px]
__device__ float g_xg[16 * NPIX * 16];     // x transposed: [d][p][cg] = x[b][16cg+d][hw]
__device__ float g_w2t[CR * KKG];          // w2T[c][o] = w2[o][c]   (64 x 784)

// ---------------- k1f: FUSED conv1(full-K)+stats | x-transpose | w2-transpose -----------
// grid (625) 1-D, block 256. Replaces old k1a(825) + kRT(25x80): kills the 6.4 MB
// g_P partial round-trip and one whole dispatch.
//   bid <  200: conv1, o-tile 8, FULL c-loop (256). XCD decode: unit=(bid&7)*25+(bid>>3)
//     so XCD x owns units [25x,25x+25) -> p-slabs [~3.1x..3.1x+3.1] (4 slabs x 256 KB
//     = 1 MB working set, each slab read 8x from L2 by the 8 o-tiles).
//     Each block also reduces its 256-px partial BN stats (sum/sumsq per o) -> g_bs,
//     same layout kB already reads.
//   bid in [200,600): x -> g_xg transpose (d-slice per block), pt co-located with the
//     conv slabs on the same XCD (t&7 selects XCD-group, matching conv's bid&7 decode).
//   bid >= 600: 25 blocks transpose w2 -> g_w2t (read by kB next dispatch).
__global__ __launch_bounds__(256) void k1f(const float* __restrict__ x,
                                           const float* __restrict__ w1,
                                           const float* __restrict__ b1,
                                           const float* __restrict__ w2) {
  int bid = blockIdx.x;
  if (bid >= 600) {
    int t = bid - 600;
    int idx = t * 256 + threadIdx.x;
    for (int j = idx; j < CR * KKG; j += 25 * 256) {
      int c = j / KKG, o = j - c * KKG;      // w2T[c*784+o] = w2[o*64+c]
      g_w2t[j] = w2[o * CR + c];
    }
    return;
  }
  if (bid >= 200) {
    // x transpose: 400 blocks = 25 pt x 16 d. XCD co-location with conv slabs:
    // g = (t&7)*50 + (t>>3); pt = g>>4 spans [~3.1x, 3.1x+3.1) on XCD x.
    int t  = bid - 200;                      // 200%8==0 -> XCD = t&7
    int g  = (t & 7) * 50 + (t >> 3);        // bijective over [0,400)
    int pt = g >> 4;
    int d  = g & 15;
    int p  = pt * 256 + threadIdx.x;
    if (p >= NPIX) return;
    int b  = (p >= HW) ? 1 : 0;
    int hw = p - b * HW;
    const float* xp = x + ((size_t)(b * C_IN + d)) * HW + hw;
    float r[16];
#pragma unroll
    for (int cg = 0; cg < 16; ++cg)
      r[cg] = xp[(size_t)cg * (16 * HW)];
    float4* dst = (float4*)(g_xg + (((size_t)d * NPIX + p) << 4));
    dst[0] = make_float4(r[0], r[1], r[2], r[3]);
    dst[1] = make_float4(r[4], r[5], r[6], r[7]);
    dst[2] = make_float4(r[8], r[9], r[10], r[11]);
    dst[3] = make_float4(r[12], r[13], r[14], r[15]);
    return;
  }
  // conv1 + per-block BN partial stats: 200 blocks = 25 pt x 8 o-tiles.
  int unit = (bid & 7) * 25 + (bid >> 3);    // bijective over [0,200)
  int pt   = unit >> 3;                      // [0,25)
  int o0   = (unit & 7) * 8;                 // o-tile of 8
  int p    = pt * 256 + threadIdx.x;
  bool valid = (p < NPIX);
  int pc   = valid ? p : 0;                  // clamp: last tile is half-empty
  int b    = pc / HW;
  int u    = pc - b * HW;

  const float* xb = x + (size_t)(b * C_IN) * HW + u;

  float acc[8];
#pragma unroll
  for (int i = 0; i < 8; ++i) acc[i] = b1[o0 + i];
#pragma unroll 8
  for (int c = 0; c < C_IN; ++c) {
    float xv = xb[(size_t)c * HW];           // coalesced across lanes, L2-resident slab
#pragma unroll
    for (int i = 0; i < 8; ++i)
      acc[i] += w1[(o0 + i) * C_IN + c] * xv;  // wave-uniform -> s_load
  }
  if (valid) {
    float* pp = g_T + (size_t)o0 * NPIX + p;
#pragma unroll
    for (int i = 0; i < 8; ++i) pp[(size_t)i * NPIX] = acc[i];
  }
  // Block-level BN partials: sum and sumsq per o over this block's 256 px.
  __shared__ float red[16][4];
  int lane = threadIdx.x & 63, wid = threadIdx.x >> 6;
#pragma unroll
  for (int i = 0; i < 8; ++i) {
    float s  = valid ? acc[i] : 0.0f;
    float s2 = s * s;
#pragma unroll
    for (int off = 32; off > 0; off >>= 1) {
      s  += __shfl_down(s, off);
      s2 += __shfl_down(s2, off);
    }
    if (lane == 0) { red[i][wid] = s; red[8 + i][wid] = s2; }
  }
  __syncthreads();
  if (threadIdx.x < 8) {
    int i = threadIdx.x;
    g_bs[(o0 + i) * NT25 + pt] = red[i][0] + red[i][1] + red[i][2] + red[i][3];
  } else if (threadIdx.x < 16) {
    int i = threadIdx.x - 8;
    g_bs[CR * NT25 + (o0 + i) * NT25 + pt] =
        red[8 + i][0] + red[8 + i][1] + red[8 + i][2] + red[8 + i][3];
  }
}

// ---------------- kB: kout = w2 @ relu(BN(T)) + b2, BN finalized per-block ----------------
// grid (13, 49, 2), block 256. Each block: 16 output channels x 256 pixels.
// Weights via g_w2t: 64B contiguous per c-iter -> wide s_load.
__global__ __launch_bounds__(256) void kB_conv2(const float* __restrict__ gamma,
                                                const float* __restrict__ beta,
                                                const float* __restrict__ b2,
                                                float* __restrict__ kout) {
  __shared__ float ssc[CR], ssh[CR];
  if (threadIdx.x < CR) {
    int o = threadIdx.x;
    float S = 0.f, S2 = 0.f;
#pragma unroll
    for (int px = 0; px < NT25; ++px) {
      S  += g_bs[o * NT25 + px];
      S2 += g_bs[CR * NT25 + o * NT25 + px];
    }
    const float invN = 1.0f / (float)NPIX;
    float mean = S * invN;
    float var  = S2 * invN - mean * mean;   // population var matches jnp.var
    float inv  = rsqrtf(var + BN_EPS);
    float sc   = gamma[o] * inv;
    ssc[o] = sc;
    ssh[o] = beta[o] - mean * sc;
  }
  __syncthreads();

  int l  = blockIdx.x * 256 + threadIdx.x;
  if (l >= HW) return;
  int o0 = blockIdx.y * 16;
  int b  = blockIdx.z;

  float acc[16];
#pragma unroll
  for (int i = 0; i < 16; ++i) acc[i] = b2[o0 + i];

  const float* Tb = g_T + (size_t)b * HW + l;     // g_T[c*NPIX + b*HW + l]
  const float* wt = g_w2t + o0;                   // w2T[c*784 + o], 64B-aligned rows
#pragma unroll 4
  for (int c = 0; c < CR; ++c) {
    float tv = Tb[(size_t)c * NPIX];
    tv = fmaxf(tv * ssc[c] + ssh[c], 0.0f);       // fused BN + ReLU (LDS broadcast)
#pragma unroll
    for (int i = 0; i < 16; ++i)
      acc[i] += wt[c * KKG + i] * tv;             // contiguous uniform -> wide s_load
  }
  float* kb = kout + (size_t)(b * KKG + o0) * HW + l;
#pragma unroll
  for (int i = 0; i < 16; ++i) kb[(size_t)i * HW] = acc[i];
}

// ---------------- K4: involution, s-per-block, FULL-LINE x_g loads (16 cg/thread) ----
// out[b][16cg+s][u] = sum_kk kout[b][16kk+s][u] * x_g[d][b*HW+pix][cg]
//   d=(16kk+s)/49, kk'=(16kk+s)%49, ki=kk'/7, kj=kk'%7,
//   pix=(u/56+ki-3)*56 + (u%56+kj-3), term dropped if OOB.
// grid (16, 13, 2), block 256: x=s (uniform, fastest -> XCD spread shares u-tile),
// y=u-tile, z=b. Each lane reads one full 64B x_g line per tap (zero line waste),
// each kout element read exactly once. (Round-1 XCD co-location swizzle REGRESSED
// 124->130 us -- this round-0 mapping is the verified-best; all blocks co-resident,
// same-s blocks sweep each d-slice in lockstep so the slice stays L2-hot.)
__global__ __launch_bounds__(256) void k4_invol(const float* __restrict__ kout,
                                                float* __restrict__ out) {
  int u = blockIdx.y * 256 + threadIdx.x;     // [0, 3136)
  if (u >= HW) return;
  int s = blockIdx.x;                          // wave-uniform
  int b = blockIdx.z;

  int yrow = u / 56;
  int col  = u - yrow * 56;

  const float* kb = kout + (size_t)b * (KKG * HW) + (size_t)s * HW + u;
  const size_t bHW16 = (size_t)(b * HW) << 4;

  float acc[16];
#pragma unroll
  for (int i = 0; i < 16; ++i) acc[i] = 0.0f;

#pragma unroll 7
  for (int kk = 0; kk < 49; ++kk) {
    int t16 = 16 * kk + s;          // scalar
    int d   = t16 / 49;             // scalar (SALU magic-mul)
    int kkp = t16 - d * 49;         // scalar
    int ki  = kkp / 7;              // scalar
    int kj  = kkp - ki * 7;         // scalar
    int yy = yrow + ki - 3, xx = col + kj - 3;
    float kv = kb[(size_t)kk * (16 * HW)];
    int off;
    if ((unsigned)yy < 56u && (unsigned)xx < 56u) {
      off = yy * 56 + xx;
    } else {
      off = 0;                      // safe address; kv=0 kills the term
      kv = 0.0f;
    }
    const float* xp = g_xg + (((size_t)d * NPIX + off) << 4) + bHW16;
    float4 x0 = *(const float4*)xp;
    float4 x1 = *(const float4*)(xp + 4);
    float4 x2 = *(const float4*)(xp + 8);
    float4 x3 = *(const float4*)(xp + 12);
    acc[0]  += kv * x0.x;  acc[1]  += kv * x0.y;
    acc[2]  += kv * x0.z;  acc[3]  += kv * x0.w;
    acc[4]  += kv * x1.x;  acc[5]  += kv * x1.y;
    acc[6]  += kv * x1.z;  acc[7]  += kv * x1.w;
    acc[8]  += kv * x2.x;  acc[9]  += kv * x2.y;
    acc[10] += kv * x2.z;  acc[11] += kv * x2.w;
    acc[12] += kv * x3.x;  acc[13] += kv * x3.y;
    acc[14] += kv * x3.z;  acc[15] += kv * x3.w;
  }

  // out channel c = 16*cg + s
  float* ob = out + (size_t)b * (C_IN * HW) + (size_t)s * HW + u;
#pragma unroll
  for (int cg = 0; cg < 16; ++cg) ob[(size_t)cg * (16 * HW)] = acc[cg];
}

extern "C" void kernel_launch(void* const* d_in, const int* in_sizes, int n_in,
                              void* d_out, int out_size, void* d_ws, size_t ws_size,
                              hipStream_t stream) {
  const float* x     = (const float*)d_in[0];
  const float* w1    = (const float*)d_in[1];
  const float* b1    = (const float*)d_in[2];
  const float* gamma = (const float*)d_in[3];
  const float* beta  = (const float*)d_in[4];
  const float* w2    = (const float*)d_in[5];
  const float* b2    = (const float*)d_in[6];

  float* out  = (float*)d_out;                       // (B,256,56,56)
  float* kout = out + (size_t)NB * C_IN * HW;        // (B,784,56,56) raw == (B,49,56,56,16)

  k1f<<<dim3(625), 256, 0, stream>>>(x, w1, b1, w2);
  kB_conv2<<<dim3(13, 49, NB), 256, 0, stream>>>(gamma, beta, b2, kout);
  k4_invol<<<dim3(16, 13, NB), 256, 0, stream>>>(kout, out);
}

// Round 3
// 127.335 us; speedup vs baseline: 1.0426x; 1.0426x over previous
//
#include <hip/hip_runtime.h>

// Problem constants (B,C,H,W)=(2,256,56,56), Cr=64, K=7, G=16, stride=1
#define HW     3136          // 56*56
#define C_IN   256
#define CR     64
#define KKG    784           // 49*16
#define NB     2             // batch
#define NPIX   6272          // NB*HW
#define NT25   25            // p-tiles of 256 over NPIX
#define BN_EPS 1e-5f

// Device-global scratch (fully rewritten every call; no cross-call state)
__device__ float g_P[4 * CR * NPIX];       // K-split conv1 partials [kc][o][p]
__device__ float g_T[CR * NPIX];           // conv1 output (pre-BN) [o][p]
__device__ float g_bs[2 * CR * NT25];      // per-block partial sum/sumsq [2][o][px]
__device__ float g_xg[16 * NPIX * 16];     // x transposed: [d][p][cg] = x[b][16cg+d][hw]
__device__ float g_w2s[16 * 49 * CR];      // w2 regrouped: [s][kk][c] = w2[16kk+s][c]

// ---------------- K1a: conv1 partials (o-tile 8, split-K 4), XCD-swizzled ----------------
// grid (825) 1-D, block 256.  (ROUND-0 VERIFIED CODE -- do not restructure: the split-K
// "extra" 12.8 MB g_P round-trip buys 800 blocks of latency hiding; the 200-block
// full-K fusion (round 2) regressed 124->133 us.)
//   bid < 800: conv partials. XCD decode: kc = (bid%8)>>1 -> each kc x-slice stays
//     L2-resident on its XCD-pair across its 200 re-reading blocks.
//   bid >= 800: 25 blocks regroup w2 -> g_w2s (read by k45 two dispatches later).
__global__ __launch_bounds__(256) void k1a_conv1(const float* __restrict__ x,
                                                 const float* __restrict__ w1,
                                                 const float* __restrict__ w2) {
  int bid = blockIdx.x;
  if (bid >= 800) {
    int t = bid - 800;
    int idx = t * 256 + threadIdx.x;
    for (int j = idx; j < 16 * 49 * CR; j += 25 * 256) {
      int s  = j / 3136;                   // 49*64 = 3136 per s
      int r  = j - s * 3136;
      int kk = r >> 6;
      int c  = r & 63;                     // g_w2s[s][kk][c] = w2[(16kk+s)*64 + c]
      g_w2s[j] = w2[(16 * kk + s) * CR + c];
    }
    return;
  }
  int kc     = (bid & 7) >> 1;              // constant per XCD-pair
  int parity = bid & 1;
  int unit   = (bid >> 3) * 2 + parity;     // [0, 200)
  int o0     = (unit & 7) * 8;
  int pt     = unit >> 3;                   // [0, 25)
  int p      = pt * 256 + threadIdx.x;
  if (p >= NPIX) return;
  int b = p / HW;
  int u = p - b * HW;

  const float* xb = x + ((size_t)(b * C_IN + kc * 64)) * HW + u;
  const float* w  = w1 + kc * 64;           // w1[o*256 + kc*64 + c]

  float acc[8];
#pragma unroll
  for (int i = 0; i < 8; ++i) acc[i] = 0.0f;
#pragma unroll 8
  for (int c = 0; c < 64; ++c) {
    float xv = xb[(size_t)c * HW];          // coalesced across lanes, L2-resident slice
#pragma unroll
    for (int i = 0; i < 8; ++i)
      acc[i] += w[(o0 + i) * C_IN + c] * xv;  // wave-uniform -> s_load
  }
  float* pp = g_P + ((size_t)kc * CR + o0) * NPIX + p;
#pragma unroll
  for (int i = 0; i < 8; ++i) pp[(size_t)i * NPIX] = acc[i];
}

// ---------------- kRT: fused (reduce partials -> T + partial stats) | (transpose x) ----
// grid (25, 80), block 256.  (ROUND-0 VERIFIED CODE.)
//   y in [0,64): reduce for o=y at p-tile x; write g_T and g_bs[o][px].
//   y in [64,80): transpose slice d=y-64 at p-tile x into g_xg.
__global__ __launch_bounds__(256) void kRT(const float* __restrict__ x,
                                           const float* __restrict__ b1) {
  int p = blockIdx.x * 256 + threadIdx.x;
  if (blockIdx.y < 64) {
    int o = blockIdx.y;
    bool valid = (p < NPIX);
    float v = 0.0f;
    if (valid) {
      v = b1[o]
        + g_P[((size_t)0 * CR + o) * NPIX + p]
        + g_P[((size_t)1 * CR + o) * NPIX + p]
        + g_P[((size_t)2 * CR + o) * NPIX + p]
        + g_P[((size_t)3 * CR + o) * NPIX + p];
      g_T[(size_t)o * NPIX + p] = v;
    }
    float s  = valid ? v : 0.0f;
    float s2 = valid ? v * v : 0.0f;
#pragma unroll
    for (int off = 32; off > 0; off >>= 1) {
      s  += __shfl_down(s, off);
      s2 += __shfl_down(s2, off);
    }
    __shared__ float sd[8];
    int lane = threadIdx.x & 63, wid = threadIdx.x >> 6;
    if (lane == 0) { sd[wid] = s; sd[4 + wid] = s2; }
    __syncthreads();
    if (threadIdx.x == 0) {
      g_bs[o * NT25 + blockIdx.x]             = sd[0] + sd[1] + sd[2] + sd[3];
      g_bs[CR * NT25 + o * NT25 + blockIdx.x] = sd[4] + sd[5] + sd[6] + sd[7];
    }
  } else {
    int d = blockIdx.y - 64;
    if (p >= NPIX) return;
    int b  = (p >= HW) ? 1 : 0;
    int hw = p - b * HW;
    const float* xp = x + ((size_t)(b * C_IN + d)) * HW + hw;
    float r[16];
#pragma unroll
    for (int cg = 0; cg < 16; ++cg)
      r[cg] = xp[(size_t)cg * (16 * HW)];
    float4* dst = (float4*)(g_xg + (((size_t)d * NPIX + p) << 4));
    dst[0] = make_float4(r[0], r[1], r[2], r[3]);
    dst[1] = make_float4(r[4], r[5], r[6], r[7]);
    dst[2] = make_float4(r[8], r[9], r[10], r[11]);
    dst[3] = make_float4(r[12], r[13], r[14], r[15]);
  }
}

// ---------------- k45: FUSED conv2 + involution ------------------------------------------
// Replaces kB (13,49,2) + k4 (16,13,2): k4's s-dim already partitions kout channels by
// ch % 16 == s, and kout has NO spatial halo -> block (s,ut,b) computes its own 49
// channels {16kk+s} from g_T with ZERO redundant FMA (each (ch,px) computed exactly
// once), stores them to kout (required output), and consumes them immediately.
// Removes: kB dispatch + gap, the 19.7 MB kout read-back, 49x re-reads of g_T.
// grid (16, 13, 2), block 256 -- identical wave count & x_g access pattern to the
// verified k4; kB's 3136 FMA/thread fold into the x_g load-latency idle cycles.
__global__ __launch_bounds__(256) void k45(const float* __restrict__ gamma,
                                           const float* __restrict__ beta,
                                           const float* __restrict__ b2,
                                           float* __restrict__ kout,
                                           float* __restrict__ out) {
  // BN finalize (same math/order as old kB prologue)
  __shared__ float ssc[CR], ssh[CR];
  if (threadIdx.x < CR) {
    int o = threadIdx.x;
    float S = 0.f, S2 = 0.f;
#pragma unroll
    for (int px = 0; px < NT25; ++px) {
      S  += g_bs[o * NT25 + px];
      S2 += g_bs[CR * NT25 + o * NT25 + px];
    }
    const float invN = 1.0f / (float)NPIX;
    float mean = S * invN;
    float var  = S2 * invN - mean * mean;   // population var matches jnp.var
    float inv  = rsqrtf(var + BN_EPS);
    float sc   = gamma[o] * inv;
    ssc[o] = sc;
    ssh[o] = beta[o] - mean * sc;
  }
  __syncthreads();

  int u = blockIdx.y * 256 + threadIdx.x;     // [0, 3136)
  if (u >= HW) return;                        // after the barrier
  int s = blockIdx.x;                          // wave-uniform
  int b = blockIdx.z;

  // Stage this pixel's BN+ReLU'd conv1 column in registers (read g_T ONCE per s).
  float t_reg[CR];
  const float* Tb = g_T + (size_t)b * HW + u;  // coalesced across lanes
#pragma unroll
  for (int c = 0; c < CR; ++c)
    t_reg[c] = fmaxf(fmaf(Tb[(size_t)c * NPIX], ssc[c], ssh[c]), 0.0f);

  int yrow = u / 56;
  int col  = u - yrow * 56;
  const size_t bHW16 = (size_t)(b * HW) << 4;
  float* kb = kout + (size_t)b * (KKG * HW) + (size_t)s * HW + u;
  const float* wbase = g_w2s + (size_t)s * (49 * CR);  // contiguous [kk][c] for this s

  float acc[16];
#pragma unroll
  for (int i = 0; i < 16; ++i) acc[i] = 0.0f;

#pragma unroll 7
  for (int kk = 0; kk < 49; ++kk) {
    // ---- conv2 for channel t16 = 16kk+s at pixel u (wave-uniform wide s_loads) ----
    const float* wrow = wbase + kk * CR;
    float kv0 = 0.f, kv1 = 0.f, kv2 = 0.f, kv3 = 0.f;   // 4-way ILP split
#pragma unroll
    for (int c = 0; c < CR; c += 4) {
      kv0 = fmaf(wrow[c + 0], t_reg[c + 0], kv0);
      kv1 = fmaf(wrow[c + 1], t_reg[c + 1], kv1);
      kv2 = fmaf(wrow[c + 2], t_reg[c + 2], kv2);
      kv3 = fmaf(wrow[c + 3], t_reg[c + 3], kv3);
    }
    int t16 = 16 * kk + s;                   // scalar
    float kv = b2[t16] + ((kv0 + kv1) + (kv2 + kv3));
    kb[(size_t)kk * (16 * HW)] = kv;         // kout is a required output: store true kv

    // ---- involution tap ----
    int d   = t16 / 49;                      // scalar (SALU magic-mul)
    int kkp = t16 - d * 49;
    int ki  = kkp / 7;
    int kj  = kkp - ki * 7;
    int yy = yrow + ki - 3, xx = col + kj - 3;
    int off;
    if ((unsigned)yy < 56u && (unsigned)xx < 56u) {
      off = yy * 56 + xx;
    } else {
      off = 0;                               // safe address; kv=0 kills the term
      kv = 0.0f;
    }
    const float* xp = g_xg + (((size_t)d * NPIX + off) << 4) + bHW16;
    float4 x0 = *(const float4*)xp;
    float4 x1 = *(const float4*)(xp + 4);
    float4 x2 = *(const float4*)(xp + 8);
    float4 x3 = *(const float4*)(xp + 12);
    acc[0]  += kv * x0.x;  acc[1]  += kv * x0.y;
    acc[2]  += kv * x0.z;  acc[3]  += kv * x0.w;
    acc[4]  += kv * x1.x;  acc[5]  += kv * x1.y;
    acc[6]  += kv * x1.z;  acc[7]  += kv * x1.w;
    acc[8]  += kv * x2.x;  acc[9]  += kv * x2.y;
    acc[10] += kv * x2.z;  acc[11] += kv * x2.w;
    acc[12] += kv * x3.x;  acc[13] += kv * x3.y;
    acc[14] += kv * x3.z;  acc[15] += kv * x3.w;
  }

  // out channel c = 16*cg + s
  float* ob = out + (size_t)b * (C_IN * HW) + (size_t)s * HW + u;
#pragma unroll
  for (int cg = 0; cg < 16; ++cg) ob[(size_t)cg * (16 * HW)] = acc[cg];
}

extern "C" void kernel_launch(void* const* d_in, const int* in_sizes, int n_in,
                              void* d_out, int out_size, void* d_ws, size_t ws_size,
                              hipStream_t stream) {
  const float* x     = (const float*)d_in[0];
  const float* w1    = (const float*)d_in[1];
  const float* b1    = (const float*)d_in[2];
  const float* gamma = (const float*)d_in[3];
  const float* beta  = (const float*)d_in[4];
  const float* w2    = (const float*)d_in[5];
  const float* b2    = (const float*)d_in[6];

  float* out  = (float*)d_out;                       // (B,256,56,56)
  float* kout = out + (size_t)NB * C_IN * HW;        // (B,784,56,56) raw == (B,49,56,56,16)

  k1a_conv1<<<dim3(825), 256, 0, stream>>>(x, w1, w2);
  kRT<<<dim3(25, 80), 256, 0, stream>>>(x, b1);
  k45<<<dim3(16, 13, NB), 256, 0, stream>>>(gamma, beta, b2, kout, out);
}